// Round 1
// baseline (243.385 us; speedup 1.0000x reference)
//
#include <hip/hip_runtime.h>

#define NQ 12
#define DEPTH 8
#define NCLASS 10
#define BATCH 4096

// ---------------------------------------------------------------------------
// Layout: one wave (64 lanes) per sample. Amplitude index i (12 bits):
//   i = lane*64 + j   (j = per-thread register index, v[64])
//   qubit q in 0..5  <-> lane bit (5-q)   (PennyLane wire0 = MSB)
//   qubit q in 6..11 <-> reg  bit (11-q)
// CNOT source-map composition per layer (gates: even CNOTs, odd CNOTs, RYs):
//   even group: lane perm sigE (bpermute), local perm sigL1 (register rename)
//   odd  group: lane perm sigO (bpermute), CNOT(5,6) = cndmask on lane bit0
//               targeting reg bit5, local perm sigL2 (rename)
// ---------------------------------------------------------------------------

__device__ __forceinline__ float bperm(int addr, float x) {
    return __int_as_float(__builtin_amdgcn_ds_bpermute(addr, __float_as_int(x)));
}

__device__ constexpr int sigL1(int j) {  // even local CNOTs (6,7),(8,9),(10,11)
    return j ^ ((((j >> 5) & 1) << 4) | (((j >> 3) & 1) << 2) | ((j >> 1) & 1));
}
__device__ constexpr int gO(int j) {     // odd local CNOTs (7,8),(9,10)
    return j ^ ((((j >> 4) & 1) << 3) | (((j >> 2) & 1) << 1));
}

__global__ __launch_bounds__(256) void vqc_kernel(const float* __restrict__ X,
                                                  const float* __restrict__ W,
                                                  float* __restrict__ out) {
    const int lane   = threadIdx.x & 63;
    const int sample = (int)((blockIdx.x * blockDim.x + threadIdx.x) >> 6);
    const int l = lane;

    // precomputed cross-lane gather addresses (bytes = lane*4)
    const int lsE = l ^ ((((l >> 5) & 1) << 4) | (((l >> 3) & 1) << 2) | ((l >> 1) & 1));
    const int lsO = l ^ ((((l >> 4) & 1) << 3) | (((l >> 2) & 1) << 1));
    const int addrE = lsE << 2;
    const int addrO = lsO << 2;
    int addrX[6];
#pragma unroll
    for (int m = 0; m < 6; ++m) addrX[m] = (l ^ (1 << m)) << 2;
    const bool b0 = (l & 1) != 0;   // control of CNOT(5,6) = lane bit0

    // ---- data encoding: build product state directly ----
    float cx[NQ], sx[NQ];
#pragma unroll
    for (int q = 0; q < NQ; ++q) {
        float ang = 0.5f * X[sample * NQ + q] + 0.78539816339744831f;
        __sincosf(ang, &sx[q], &cx[q]);
    }
    float P = 1.0f;
#pragma unroll
    for (int q = 0; q < 6; ++q) P *= ((l >> (5 - q)) & 1) ? sx[q] : cx[q];

    float v[64];
    v[0] = P * cx[11];
    v[1] = P * sx[11];
#pragma unroll
    for (int lvl = 1; lvl < 6; ++lvl) {
        const int q = 11 - lvl;               // qubit for reg bit 'lvl'
#pragma unroll
        for (int j = 0; j < (1 << 5); ++j) {  // bound folded below by guard
            if (j >= (1 << lvl)) continue;
            v[j + (1 << lvl)] = v[j] * sx[q];
            v[j]              = v[j] * cx[q];
        }
    }

    // ---- variational layers ----
#pragma unroll 1
    for (int k = 0; k < DEPTH; ++k) {
        float wv[NQ];
#pragma unroll
        for (int q = 0; q < NQ; ++q) wv[q] = W[k * NQ + q];

        // CNOT even group: v_new[j] = from lane lsE, local sigL1(j)
#pragma unroll
        for (int j = 0; j < 64; ++j) {
            const int pj = sigL1(j);
            if (pj == j) {
                v[j] = bperm(addrE, v[j]);
            } else if (pj > j) {
                float ta = bperm(addrE, v[pj]);   // dest j
                float tb = bperm(addrE, v[j]);    // dest pj
                v[j] = ta;
                v[pj] = tb;
            }
        }
        // CNOT odd group: v_new[j] = from lane lsO, local gO(j) ^ (b0<<5)
#pragma unroll
        for (int j = 0; j < 32; ++j) {
            const int j2 = gO(j);
            if (j2 == j) {
                float t0 = b0 ? v[j + 32] : v[j];        // dest j
                float t1 = b0 ? v[j]      : v[j + 32];   // dest j+32
                float r0 = bperm(addrO, t0);
                float r1 = bperm(addrO, t1);
                v[j] = r0;
                v[j + 32] = r1;
            } else if (j2 > j) {
                float t0 = b0 ? v[j2 + 32] : v[j2];      // dest j
                float t1 = b0 ? v[j + 32]  : v[j];       // dest j2
                float t2 = b0 ? v[j2]      : v[j2 + 32]; // dest j+32
                float t3 = b0 ? v[j]       : v[j + 32];  // dest j2+32
                float r0 = bperm(addrO, t0);
                float r1 = bperm(addrO, t1);
                float r2 = bperm(addrO, t2);
                float r3 = bperm(addrO, t3);
                v[j] = r0;
                v[j2] = r1;
                v[j + 32] = r2;
                v[j2 + 32] = r3;
            }
        }

        // RY on all 12 qubits (they commute)
#pragma unroll
        for (int q = 0; q < NQ; ++q) {
            float cw, sw;
            __sincosf(0.5f * wv[q], &sw, &cw);
            if (q < 6) {
                // lane qubit: partner across lane bit (5-q)
                const int mb = 5 - q;
                const float se = ((l >> mb) & 1) ? sw : -sw;
#pragma unroll
                for (int j = 0; j < 64; ++j) {
                    float p = bperm(addrX[mb], v[j]);
                    v[j] = cw * v[j] + se * p;
                }
            } else {
                // local qubit: pairs across reg bit (11-q)
                const int lb = 11 - q;
#pragma unroll
                for (int j = 0; j < 64; ++j) {
                    if (j & (1 << lb)) continue;
                    const int j1 = j | (1 << lb);
                    float a = v[j], b = v[j1];
                    v[j]  = cw * a - sw * b;
                    v[j1] = sw * a + cw * b;
                }
            }
        }
    }

    // ---- measurement: <Z_p> = sum probs(bit=0) - sum probs(bit=1) ----
#pragma unroll
    for (int j = 0; j < 64; ++j) v[j] *= v[j];

    float c2[16];  // summed over reg bits 0,1; indexed by reg bits 5..2
#pragma unroll
    for (int m = 0; m < 16; ++m)
        c2[m] = (v[4 * m] + v[4 * m + 1]) + (v[4 * m + 2] + v[4 * m + 3]);

    float S = 0.0f;
#pragma unroll
    for (int m = 0; m < 16; ++m) S += c2[m];

    float T[4];  // T[t]: signed on m-bit t  (reg bit t+2)
#pragma unroll
    for (int t = 0; t < 4; ++t) {
        float acc = 0.0f;
#pragma unroll
        for (int m = 0; m < 16; ++m) acc += ((m >> t) & 1) ? -c2[m] : c2[m];
        T[t] = acc;
    }

    float o[NCLASS];
#pragma unroll
    for (int p = 0; p < 6; ++p) {   // qubit p on lane bit (5-p)
        float r = ((l >> (5 - p)) & 1) ? -S : S;
#pragma unroll
        for (int m = 0; m < 6; ++m) r += __shfl_xor(r, 1 << m, 64);
        o[p] = r;
    }
#pragma unroll
    for (int p = 6; p < 10; ++p) {  // qubit p on reg bit (11-p) -> T[9-p]
        float r = T[9 - p];
#pragma unroll
        for (int m = 0; m < 6; ++m) r += __shfl_xor(r, 1 << m, 64);
        o[p] = r;
    }

    if (lane == 0) {
#pragma unroll
        for (int p = 0; p < NCLASS; ++p) out[sample * NCLASS + p] = o[p];
    }
}

extern "C" void kernel_launch(void* const* d_in, const int* in_sizes, int n_in,
                              void* d_out, int out_size, void* d_ws, size_t ws_size,
                              hipStream_t stream) {
    const float* X = (const float*)d_in[0];
    const float* W = (const float*)d_in[1];
    float* out     = (float*)d_out;
    (void)in_sizes; (void)n_in; (void)out_size; (void)d_ws; (void)ws_size;

    dim3 grid(BATCH / 4);   // 4 waves = 4 samples per 256-thread block
    dim3 block(256);
    hipLaunchKernelGGL(vqc_kernel, grid, block, 0, stream, X, W, out);
}

// Round 2
// 151.638 us; speedup vs baseline: 1.6050x; 1.6050x over previous
//
#include <hip/hip_runtime.h>

#define NQ 12
#define DEPTH 8
#define NCLASS 10
#define BATCH 4096
#define LSTRIDE 68   // LDS row stride in floats (mult of 4 for b128; 4l+x bank pattern => <=2-way)
#define WPB 2        // waves (= samples) per block; LDS = 2*64*68*4 = 34816 B

// ---------------------------------------------------------------------------
// One wave per sample; statevector (4096 amps) lives in v[64] per lane.
// Frame A: qubit q in 0..5  <-> lane bit (5-q);  q in 6..11 <-> reg bit (11-q)
// Frame B: qubit q in 0..5  <-> reg  bit (5-q);  q in 6..11 <-> lane bit (11-q)
// Per layer:
//   RT1: LDS round-trip implementing (transpose ∘ CNOT_odd ∘ CNOT_even), A->B
//        gather index: src_lane = h(r) (compile-time), src_col = g(l) ^ (r&1 ? 0x30 : 0)
//        (the ^0x30 is CNOT(5,6): control qubit5 = r bit0, target qubit6->cols)
//   RY qubits 0..5   (reg-local in frame B, pure VALU)
//   RT2: plain transpose B->A
//   RY qubits 6..11  (reg-local in frame A, pure VALU)
// All DS ops are intra-wave (private LDS region per wave; DS is in-order) -> no barriers.
// ---------------------------------------------------------------------------

// source lane for RT1 output reg r: qubit bits c0..c5 from r after C_odd,C_even index maps
__device__ constexpr int hfun(int r) {
    const int rb5 = (r >> 5) & 1, rb4 = (r >> 4) & 1, rb3 = (r >> 3) & 1;
    const int rb2 = (r >> 2) & 1, rb1 = (r >> 1) & 1, rb0 = r & 1;
    const int c0 = rb5;
    const int c1 = rb4 ^ rb5;
    const int c2 = rb3 ^ rb4;
    const int c3 = rb2 ^ rb3 ^ rb4;
    const int c4 = rb1 ^ rb2;
    const int c5 = rb0 ^ rb1 ^ rb2;
    return (c0 << 5) | (c1 << 4) | (c2 << 3) | (c3 << 2) | (c4 << 1) | c5;
}

__global__ __launch_bounds__(WPB * 64) void vqc_kernel(const float* __restrict__ X,
                                                       const float* __restrict__ W,
                                                       float* __restrict__ out) {
    __shared__ __align__(16) float lds[WPB * 64 * LSTRIDE];

    const int lane   = threadIdx.x & 63;
    const int wid    = threadIdx.x >> 6;
    const int sample = blockIdx.x * WPB + wid;
    const int l      = lane;

    float* Wb = &lds[wid * 64 * LSTRIDE];
    float4* wrow = (float4*)&Wb[l * LSTRIDE];        // row-major write, b128 x16
    // g(l): src column l-part for RT1 (CNOT chain on qubits 6..11 folded)
    const int G = l ^ (l >> 1) ^ ((l >> 2) & 5);
    const float* rG0 = &Wb[G];                        // r even (q5=0)
    const float* rG1 = &Wb[G ^ 0x30];                 // r odd  (q5=1): CNOT(5,6) column flip
    const float* rT2 = &Wb[l];                        // RT2 read base: LDS[j*S + l]

    // ---- data encoding: product state, frame A ----
    float cx[NQ], sx[NQ];
#pragma unroll
    for (int q = 0; q < NQ; ++q) {
        float ang = 0.5f * X[sample * NQ + q] + 0.78539816339744831f;
        __sincosf(ang, &sx[q], &cx[q]);
    }
    float P = 1.0f;
#pragma unroll
    for (int q = 0; q < 6; ++q) P *= ((l >> (5 - q)) & 1) ? sx[q] : cx[q];

    float v[64];
    v[0] = P * cx[11];
    v[1] = P * sx[11];
#pragma unroll
    for (int lvl = 1; lvl < 6; ++lvl) {
        const int q = 11 - lvl;
#pragma unroll
        for (int j = 0; j < (1 << 5); ++j) {
            if (j >= (1 << lvl)) continue;
            v[j + (1 << lvl)] = v[j] * sx[q];
            v[j]              = v[j] * cx[q];
        }
    }

    // ---- variational layers ----
#pragma unroll 1
    for (int k = 0; k < DEPTH; ++k) {
        // ---- RT1: frame A -> frame B with both CNOT groups folded ----
#pragma unroll
        for (int t = 0; t < 16; ++t)
            wrow[t] = make_float4(v[4 * t], v[4 * t + 1], v[4 * t + 2], v[4 * t + 3]);
#pragma unroll
        for (int r = 0; r < 64; ++r)
            v[r] = ((r & 1) ? rG1 : rG0)[hfun(r) * LSTRIDE];

        // ---- RY qubits 0..5 (frame B: qubit p <-> reg bit 5-p) ----
#pragma unroll
        for (int p = 0; p < 6; ++p) {
            float cw, sw;
            __sincosf(0.5f * W[k * NQ + p], &sw, &cw);
            const int m = 1 << (5 - p);
#pragma unroll
            for (int r = 0; r < 64; ++r) {
                if (!(r & m)) {
                    const int r1 = r | m;
                    const float a = v[r], b = v[r1];
                    v[r]  = cw * a - sw * b;
                    v[r1] = sw * a + cw * b;
                }
            }
        }

        // ---- RT2: plain transpose, frame B -> frame A ----
#pragma unroll
        for (int t = 0; t < 16; ++t)
            wrow[t] = make_float4(v[4 * t], v[4 * t + 1], v[4 * t + 2], v[4 * t + 3]);
#pragma unroll
        for (int j = 0; j < 64; ++j)
            v[j] = rT2[j * LSTRIDE];

        // ---- RY qubits 6..11 (frame A: qubit p <-> reg bit 11-p) ----
#pragma unroll
        for (int p = 6; p < NQ; ++p) {
            float cw, sw;
            __sincosf(0.5f * W[k * NQ + p], &sw, &cw);
            const int m = 1 << (11 - p);
#pragma unroll
            for (int r = 0; r < 64; ++r) {
                if (!(r & m)) {
                    const int r1 = r | m;
                    const float a = v[r], b = v[r1];
                    v[r]  = cw * a - sw * b;
                    v[r1] = sw * a + cw * b;
                }
            }
        }
    }

    // ---- measurement: <Z_p> = P(bit p = 0) - P(bit p = 1), frame A ----
#pragma unroll
    for (int j = 0; j < 64; ++j) v[j] *= v[j];

    float c2[16];  // summed over reg bits 0,1
#pragma unroll
    for (int m = 0; m < 16; ++m)
        c2[m] = (v[4 * m] + v[4 * m + 1]) + (v[4 * m + 2] + v[4 * m + 3]);

    float S = 0.0f;
#pragma unroll
    for (int m = 0; m < 16; ++m) S += c2[m];

    float T[4];  // signed sum on reg bit t+2
#pragma unroll
    for (int t = 0; t < 4; ++t) {
        float acc = 0.0f;
#pragma unroll
        for (int m = 0; m < 16; ++m) acc += ((m >> t) & 1) ? -c2[m] : c2[m];
        T[t] = acc;
    }

    float o[NCLASS];
#pragma unroll
    for (int p = 0; p < 6; ++p) {   // qubit p on lane bit (5-p)
        float r = ((l >> (5 - p)) & 1) ? -S : S;
#pragma unroll
        for (int m = 0; m < 6; ++m) r += __shfl_xor(r, 1 << m, 64);
        o[p] = r;
    }
#pragma unroll
    for (int p = 6; p < 10; ++p) {  // qubit p on reg bit (11-p) -> T[9-p]
        float r = T[9 - p];
#pragma unroll
        for (int m = 0; m < 6; ++m) r += __shfl_xor(r, 1 << m, 64);
        o[p] = r;
    }

    if (lane == 0) {
#pragma unroll
        for (int p = 0; p < NCLASS; ++p) out[sample * NCLASS + p] = o[p];
    }
}

extern "C" void kernel_launch(void* const* d_in, const int* in_sizes, int n_in,
                              void* d_out, int out_size, void* d_ws, size_t ws_size,
                              hipStream_t stream) {
    const float* X = (const float*)d_in[0];
    const float* W = (const float*)d_in[1];
    float* out     = (float*)d_out;
    (void)in_sizes; (void)n_in; (void)out_size; (void)d_ws; (void)ws_size;

    dim3 grid(BATCH / WPB);
    dim3 block(WPB * 64);
    hipLaunchKernelGGL(vqc_kernel, grid, block, 0, stream, X, W, out);
}